// Round 3
// baseline (439.412 us; speedup 1.0000x reference)
//
#include <hip/hip_runtime.h>

// Problem constants (fixed by setup_inputs / reference)
#define BB 8
#define CC 32
#define HH 512
#define WW 512
#define NN 64
#define RH 16      // HEIGHT
#define RW 128     // MAX_W
#define HWSZ (HH * WW)

#define RES_ELEMS ((size_t)BB * NN * CC * RH * RW)   // 33,554,432

// 4-byte-aligned float pair: lets LLVM emit global_load_dwordx2 at align-4
// (gfx950 unaligned-access-mode) instead of two scalar dword loads.
struct __attribute__((aligned(4))) f2 { float x, y; };

// One block = one (b,n) x 8-channel group. 256 threads: k = tid&127,
// jh = tid>>7 -> this thread owns rows j = jh*8..jh*8+7 for its fixed k,
// across 8 channels. Coordinates/weights/offsets are computed ONCE and
// reused for all 8 channels (plane base is wave-uniform -> SGPR; the
// per-lane 32-bit voffset VGPRs are reused across channels with zero
// additional address VALU).
//
// Edge handling is folded into the weights: at the x-clamp (xx==511) and
// y-clamp (yy==511) the reference's bilinear weights are exactly zero, so
// plain A.x/A.y/B.x/B.y with zeroed weights reproduces it. Inactive lanes
// (k >= new_w) get wx0=wx1=0 -> val==0, single non-divergent path; clamped
// coords keep all gather addresses in-bounds.
__global__ __launch_bounds__(256) void roi_fused(const float* __restrict__ img,
                                                 const float* __restrict__ boxes,
                                                 float* __restrict__ out,
                                                 float* __restrict__ mout) {
    const int tid = threadIdx.x;
    const int k   = tid & (RW - 1);      // 0..127
    const int jh  = tid >> 7;            // 0..1
    const unsigned blk = blockIdx.x;
    const int cg  = blk & 3;             // channel group (8 channels each)
    const int bn  = blk >> 2;            // b*NN + n
    const int b   = bn >> 6;

    const float* bx = boxes + (size_t)bn * 5;
    const float left = bx[0];
    const float top  = bx[1];
    const float bw   = bx[2] - left;
    const float bh   = bx[3] - top;
    const float aspect = (bh > 0.0f) ? (bw / fmaxf(bh, 1e-6f)) : 0.0f;
    int new_w = (int)(aspect * (float)RH);          // trunc == astype(int32)
    new_w = min(max(new_w, 0), RW);
    const float each_w = bw / (float)max(new_w - 1, 1);
    const float each_h = bh / (float)(RH - 1);

    // mask[b][n][k], written once per (b,n)
    if (cg == 0 && jh == 0)
        mout[(size_t)bn * RW + k] = (k < new_w) ? 1.0f : 0.0f;

    const bool active = (k < new_w);

    // x-setup (fixed per thread)
    const float xx = (float)k * each_w + left;
    int x0 = (int)floorf(xx);
    x0 = min(max(x0, 0), WW - 1);
    const int x1 = min(x0 + 1, WW - 1);
    const int xg = min(x0, WW - 2);                 // safe dwordx2 base
    float wx1 = (float)x1 - xx;
    float wx0 = xx - (float)x0;
    if (!active) { wx1 = 0.0f; wx0 = 0.0f; }        // masked lanes -> val 0

    // y-setup for the 8 rows this thread owns; weight products precomputed
    int   offA[8], offB[8];
    float w00[8], w01[8], w10[8], w11[8];
    #pragma unroll
    for (int jj = 0; jj < 8; ++jj) {
        const int j = jh * 8 + jj;
        const float yy = (float)j * each_h + top;
        int y0 = (int)floorf(yy);
        y0 = min(max(y0, 0), HH - 1);
        const int y1 = min(y0 + 1, HH - 1);
        const float wy1 = (float)y1 - yy;
        const float wy0 = yy - (float)y0;
        offA[jj] = y0 * WW + xg;
        offB[jj] = y1 * WW + xg;
        w00[jj] = wx1 * wy1;     // * A.x (Ia)
        w10[jj] = wx0 * wy1;     // * A.y (Ic)
        w01[jj] = wx1 * wy0;     // * B.x (Ib)
        w11[jj] = wx0 * wy0;     // * B.y (Id)
    }

    const float* plane0 = img + (size_t)(b * CC + cg * 8) * HWSZ;
    float* outp0 = out + (((size_t)bn * CC + cg * 8) * RH + (size_t)jh * 8) * RW + k;

    for (int ci = 0; ci < 8; ++ci) {
        const float* pl = plane0 + (size_t)ci * HWSZ;   // uniform -> SGPR base
        float* op = outp0 + (size_t)ci * (RH * RW);
        #pragma unroll
        for (int jj = 0; jj < 8; ++jj) {
            const f2 A  = *(const f2*)(pl + offA[jj]);
            const f2 Bv = *(const f2*)(pl + offB[jj]);
            op[jj * RW] = A.x * w00[jj] + A.y * w10[jj]
                        + Bv.x * w01[jj] + Bv.y * w11[jj];
        }
    }
}

extern "C" void kernel_launch(void* const* d_in, const int* in_sizes, int n_in,
                              void* d_out, int out_size, void* d_ws, size_t ws_size,
                              hipStream_t stream) {
    const float* img   = (const float*)d_in[0];
    const float* boxes = (const float*)d_in[1];
    float* out  = (float*)d_out;
    float* mout = out + RES_ELEMS;

    const int blocks = BB * NN * 4;                  // 2048: (b,n) x 4 channel-groups
    roi_fused<<<blocks, 256, 0, stream>>>(img, boxes, out, mout);
}